// Round 5
// baseline (59.756 us; speedup 1.0000x reference)
//
#include <hip/hip_runtime.h>

typedef float f32x4 __attribute__((ext_vector_type(4)));
typedef short s16x8 __attribute__((ext_vector_type(8)));

#define NT 512
#define CB_ROW 52
#define CB_PLANE 2704          // 52*52
#define H1_CI 192              // 12*16 per output channel
#define W2_STR 264

__device__ __forceinline__ ushort f2bf(float f) {
  unsigned u = __float_as_uint(f);
  unsigned r = (u + 0x7fffu + ((u >> 16) & 1u)) >> 16;
  return (ushort)r;
}

__device__ __forceinline__ int cellbase4(int n) {   // float4 index of cell n's origin
  int b = n >> 6, gg = n & 63;
  return b * 110592 + (gg >> 3) * 4608 + (gg & 7) * 12;
}

__global__ void prep_kernel(const float* __restrict__ fw1, ushort* __restrict__ fw1b) {
  int i = blockIdx.x * 256 + threadIdx.x;            // 288*256 = 73728 exact
  fw1b[i] = f2bf(fw1[i]);
}

__global__ __launch_bounds__(NT, 6)
void fused_kernel(const float* __restrict__ x,
                  const float* __restrict__ w1, const float* __restrict__ b1,
                  const float* __restrict__ w2, const float* __restrict__ b2,
                  const ushort* __restrict__ fw1b, const float* __restrict__ fb1,
                  const float* __restrict__ fw2, const float* __restrict__ fb2,
                  float* __restrict__ out)
{
  __shared__ __align__(16) ushort cb[8112];      // 16224 B  1 cell [3][52][52] bf16
  __shared__ __align__(16) ushort h1[3072];      // 6144 B   [16 oc][12][16] bf16
  __shared__ __align__(16) ushort h2[4608];      // 9216 B   [16 cells pad][288]
  __shared__ __align__(16) ushort w2t[8448];     // 16896 B  [32 oc][264]
                                                 // total 48480 B -> 3 blocks/CU
  float* h3 = (float*)cb;                        // [4 cells][260] alias (post-rounds)
  float* lsp = (float*)cb + 1040;                // [4][4] logits alias

  const int t = threadIdx.x;
  const int w = t >> 6;
  const int lane = t & 63;
  const int r16 = lane & 15;
  const int g = lane >> 4;

  // ---- staging descriptors: 1728 float4 per cell over 512 threads (4 slots) ----
  int goff[4], eoff[4];
#pragma unroll
  for (int i = 0; i < 4; ++i) {
    int q = i * NT + t;
    int qq = q < 1728 ? q : 0;
    int c = qq / 576; int r2 = qq - c * 576;
    int y = r2 / 12;  int quad = r2 - y * 12;
    goff[i] = c * 36864 + y * 96 + quad;
    eoff[i] = c * CB_PLANE + (y + 2) * CB_ROW + 2 + quad * 4;
  }

  // ---- one-time zero (borders persist) + w2 stage ----
  for (int i = t; i < 4056; i += NT) ((uint*)cb)[i] = 0u;
  for (int i = t; i < 1536; i += NT) ((uint*)h1)[i] = 0u;
  for (int i = t; i < 2304; i += NT) ((uint*)h2)[i] = 0u;
  for (int i = t; i < 8192; i += NT) {
    int oc = i >> 8, k = i & 255;
    w2t[oc * W2_STR + k] = f2bf(w2[i]);
  }

  // ---- conv1 B-fragments in registers: lane holds w1[oc=r16][k=32s+8g..+7] ----
  s16x8 b1f[6];
#pragma unroll
  for (int s = 0; s < 6; ++s) {
    const float* p = w1 + r16 * 192 + s * 32 + g * 8;
    float4 lo = *(const float4*)p;
    float4 hi = *(const float4*)(p + 4);
    s16x8 vv;
    vv[0] = (short)f2bf(lo.x); vv[1] = (short)f2bf(lo.y);
    vv[2] = (short)f2bf(lo.z); vv[3] = (short)f2bf(lo.w);
    vv[4] = (short)f2bf(hi.x); vv[5] = (short)f2bf(hi.y);
    vv[6] = (short)f2bf(hi.z); vv[7] = (short)f2bf(hi.w);
    b1f[s] = vv;
  }
  const float b1v = b1[r16];
  const float b2v = b2[(w & 1) * 16 + r16];

  // ---- conv1 lane constants: wave w owns m-tile w (+ tile 8 rotating) ----
  const int m_w = w * 16 + r16;
  const int rowA_w = (m_w / 12) * (4 * CB_ROW) + 4 * (m_w % 12);
  const int m_8 = 128 + r16;
  const int rowA_8 = (m_8 / 12) * (4 * CB_ROW) + 4 * (m_8 % 12);

  // ---- conv2 lane constants: owner waves {2r,2r+1} for round r ----
  const int pcl = r16 < 9 ? r16 : 8;
  const int p2y = pcl / 3, p2x = pcl - 3 * p2y;
  const int lco = (g >> 1) * H1_CI + (4 * p2y + 2 * (g & 1)) * 16 + 4 * p2x;
  const int ntC = w & 1;
  const int w2base = (ntC * 16 + r16) * W2_STR;

  __syncthreads();

  const int cell0 = blockIdx.x * 4;
  const float4* x4 = (const float4*)x;

  for (int rnd = 0; rnd < 4; ++rnd) {
    // ---- stage cell (cell0+rnd): global fp32 -> bf16 LDS ----
    {
      int base = cellbase4(cell0 + rnd);
      float4 vv[4];
#pragma unroll
      for (int i = 0; i < 4; ++i)
        if (i < 3 || t < 192) vv[i] = x4[base + goff[i]];
#pragma unroll
      for (int i = 0; i < 4; ++i)
        if (i < 3 || t < 192) {
          float4 q = vv[i]; int e = eoff[i];
          *(uint*)&cb[e]     = (uint)f2bf(q.x) | ((uint)f2bf(q.y) << 16);
          *(uint*)&cb[e + 2] = (uint)f2bf(q.z) | ((uint)f2bf(q.w) << 16);
        }
    }
    __syncthreads();

    // ---- conv1 MFMA: M=144 (tile w, + tile 8 for rotating owner) ----
    const bool has8 = (w == ((2 * rnd + 4) & 7));
    f32x4 a0 = (f32x4){0.f, 0.f, 0.f, 0.f};
    f32x4 a8 = (f32x4){0.f, 0.f, 0.f, 0.f};
#pragma unroll
    for (int s = 0; s < 6; ++s) {
      int sbase = (s >> 1) * CB_PLANE + ((s & 1) * 4 + g) * CB_ROW;
      s16x8 a;
      ((uint2*)&a)[0] = *(const uint2*)&cb[sbase + rowA_w];
      ((uint2*)&a)[1] = *(const uint2*)&cb[sbase + rowA_w + 4];
      a0 = __builtin_amdgcn_mfma_f32_16x16x32_bf16(a, b1f[s], a0, 0, 0, 0);
    }
    if (has8) {
#pragma unroll
      for (int s = 0; s < 6; ++s) {
        int sbase = (s >> 1) * CB_PLANE + ((s & 1) * 4 + g) * CB_ROW;
        s16x8 a;
        ((uint2*)&a)[0] = *(const uint2*)&cb[sbase + rowA_8];
        ((uint2*)&a)[1] = *(const uint2*)&cb[sbase + rowA_8 + 4];
        a8 = __builtin_amdgcn_mfma_f32_16x16x32_bf16(a, b1f[s], a8, 0, 0, 0);
      }
    }
    // epilogue: bias+relu -> h1 (only rows/cols 0..10 are read by conv2)
#pragma unroll
    for (int rr = 0; rr < 4; ++rr) {
      int m = w * 16 + g * 4 + rr;
      int oy = m / 12, ox = m - 12 * oy;
      if (oy < 11 && ox < 11)
        h1[r16 * H1_CI + (oy + 1) * 16 + (ox + 1)] = f2bf(fmaxf(a0[rr] + b1v, 0.f));
    }
    if (has8) {
#pragma unroll
      for (int rr = 0; rr < 4; ++rr) {
        int m = 128 + g * 4 + rr;
        int oy = m / 12, ox = m - 12 * oy;
        if (oy < 11 && ox < 11)
          h1[r16 * H1_CI + (oy + 1) * 16 + (ox + 1)] = f2bf(fmaxf(a8[rr] + b1v, 0.f));
      }
    }
    __syncthreads();

    // ---- conv2 MFMA (waves 2r,2r+1): M=9(pad16), N=16 each, K=256 ----
    // overlaps the other waves' staging of round r+1
    if ((w >> 1) == rnd) {
      f32x4 c2 = (f32x4){0.f, 0.f, 0.f, 0.f};
#pragma unroll
      for (int s2 = 0; s2 < 8; ++s2) {
        int off = s2 * 384 + lco;
        s16x8 a;
        ((uint2*)&a)[0] = *(const uint2*)&h1[off];
        ((uint2*)&a)[1] = *(const uint2*)&h1[off + 16];
        uint4 qb = *(const uint4*)&w2t[w2base + s2 * 32 + g * 8];
        c2 = __builtin_amdgcn_mfma_f32_16x16x32_bf16(a, *(s16x8*)&qb, c2, 0, 0, 0);
      }
#pragma unroll
      for (int rr = 0; rr < 4; ++rr) {
        int m2 = g * 4 + rr;
        if (m2 < 9) {
          float val = fmaxf(c2[rr] + b2v, 0.f);
          h2[rnd * 288 + (ntC * 16 + r16) * 9 + m2] = f2bf(val);
        }
      }
    }
  }
  __syncthreads();

  // ---- fc1 MFMA: M=4 cells (pad16), N=256 (wave w -> n-tiles 2w,2w+1), K=288 ----
  {
    s16x8 af[9];
#pragma unroll
    for (int s = 0; s < 9; ++s) {
      uint4 qa = *(const uint4*)&h2[r16 * 288 + s * 32 + g * 8];
      af[s] = *(s16x8*)&qa;
    }
    f32x4 fa0 = (f32x4){0.f, 0.f, 0.f, 0.f};
    f32x4 fa1 = (f32x4){0.f, 0.f, 0.f, 0.f};
#pragma unroll
    for (int s = 0; s < 9; ++s) {
      uint4 q0 = *(const uint4*)(fw1b + ((2 * w) * 16 + r16) * 288 + s * 32 + g * 8);
      fa0 = __builtin_amdgcn_mfma_f32_16x16x32_bf16(af[s], *(s16x8*)&q0, fa0, 0, 0, 0);
      uint4 q1 = *(const uint4*)(fw1b + ((2 * w + 1) * 16 + r16) * 288 + s * 32 + g * 8);
      fa1 = __builtin_amdgcn_mfma_f32_16x16x32_bf16(af[s], *(s16x8*)&q1, fa1, 0, 0, 0);
    }
#pragma unroll
    for (int i = 0; i < 2; ++i) {
      f32x4 fa = i ? fa1 : fa0;
      int n = (2 * w + i) * 16 + r16;
      float fb = fb1[n];
#pragma unroll
      for (int rr = 0; rr < 4; ++rr) {
        int cell = g * 4 + rr;
        if (cell < 4) h3[cell * 260 + n] = fmaxf(fa[rr] + fb, 0.f);
      }
    }
  }
  __syncthreads();

  // ---- fc2: 16 units (4 cells x 4 logits) x 32 lanes ----
  {
    int u = t >> 5, sub = t & 31;
    int cell = u >> 2, j = u & 3;
    const float4* hp = (const float4*)&h3[cell * 260];
    const float4* wp = (const float4*)(fw2 + j * 256);
    float p = 0.f;
#pragma unroll
    for (int i = 0; i < 2; ++i) {
      int k4 = sub + 32 * i;
      float4 a = hp[k4], b = wp[k4];
      p = fmaf(a.x, b.x, p); p = fmaf(a.y, b.y, p);
      p = fmaf(a.z, b.z, p); p = fmaf(a.w, b.w, p);
    }
    p += __shfl_xor(p, 1);
    p += __shfl_xor(p, 2);
    p += __shfl_xor(p, 4);
    p += __shfl_xor(p, 8);
    p += __shfl_xor(p, 16);
    if (sub == 0) lsp[cell * 4 + j] = p + fb2[j];
  }
  __syncthreads();

  // ---- softmax + store ----
  if (t < 4) {
    float l0 = lsp[t * 4 + 0], l1 = lsp[t * 4 + 1],
          l2 = lsp[t * 4 + 2], l3 = lsp[t * 4 + 3];
    float m = fmaxf(fmaxf(l0, l1), fmaxf(l2, l3));
    float e0 = __expf(l0 - m), e1 = __expf(l1 - m),
          e2 = __expf(l2 - m), e3 = __expf(l3 - m);
    float inv = 1.f / (e0 + e1 + e2 + e3);
    int n = cell0 + t;
    out[n] = e0 * inv;
    out[4096 + n] = e1 * inv;
    out[8192 + n] = e2 * inv;
  }
}

extern "C" void kernel_launch(void* const* d_in, const int* in_sizes, int n_in,
                              void* d_out, int out_size, void* d_ws, size_t ws_size,
                              hipStream_t stream) {
  const float* x   = (const float*)d_in[0];
  const float* w1  = (const float*)d_in[1];
  const float* b1  = (const float*)d_in[2];
  const float* w2  = (const float*)d_in[3];
  const float* b2  = (const float*)d_in[4];
  const float* fw1 = (const float*)d_in[5];
  const float* fb1 = (const float*)d_in[6];
  const float* fw2 = (const float*)d_in[7];
  const float* fb2 = (const float*)d_in[8];
  float* out = (float*)d_out;
  ushort* fw1b = (ushort*)d_ws;   // 147456 B bf16 copy of fw1

  hipLaunchKernelGGL(prep_kernel, dim3(288), dim3(256), 0, stream, fw1, fw1b);
  hipLaunchKernelGGL(fused_kernel, dim3(1024), dim3(NT), 0, stream,
                     x, w1, b1, w2, b2, fw1b, fb1, fw2, fb2, out);
}